// Round 10
// baseline (1178.211 us; speedup 1.0000x reference)
//
#include <hip/hip_runtime.h>
#include <hip/hip_fp16.h>

#define HIDDEN 128
#define SCAN_TILE 1024     // elements per scan block (256 threads x 4)
#define SCAN_BLOCK 256     // threads per scan block

// ---------------------------------------------------------------------------
// nontemporal helpers: __builtin_nontemporal_* wants a clang vector type,
// not HIP_vector_type<float,4>. ext_vector_type(4) is layout-identical.
// ---------------------------------------------------------------------------
typedef float cvec4 __attribute__((ext_vector_type(4)));

__device__ inline void nt_store4(float4* p, float4 v) {
    cvec4 x; x.x = v.x; x.y = v.y; x.z = v.z; x.w = v.w;
    __builtin_nontemporal_store(x, reinterpret_cast<cvec4*>(p));
}
__device__ inline float4 nt_load4(const float4* p) {
    cvec4 x = __builtin_nontemporal_load(reinterpret_cast<const cvec4*>(p));
    return make_float4(x.x, x.y, x.z, x.w);
}

// ---------------------------------------------------------------------------
// CSR build step 1: zero row counters
// ---------------------------------------------------------------------------
__global__ void zero_counts(int* __restrict__ counts, int n) {
    int i = blockIdx.x * blockDim.x + threadIdx.x;
    int stride = gridDim.x * blockDim.x;
    for (; i < n; i += stride) counts[i] = 0;
}

// CSR build step 2: histogram of row degrees; atomicAdd's return value IS
// the edge's rank within its row -> store it, so scatter needs no atomics.
__global__ void hist_kernel(const int* __restrict__ rows,
                            int* __restrict__ counts,
                            int* __restrict__ rank,
                            int E) {
    int i = blockIdx.x * blockDim.x + threadIdx.x;
    int stride = gridDim.x * blockDim.x;
    for (; i < E; i += stride) rank[i] = atomicAdd(&counts[rows[i]], 1);
}

// ---------------------------------------------------------------------------
// CSR build step 3: hierarchical exclusive scan.
// ---------------------------------------------------------------------------
__global__ void scan_partial_sums(const int* __restrict__ counts,
                                  int* __restrict__ block_sums,
                                  int n) {
    __shared__ int sdata[SCAN_BLOCK];
    int t = threadIdx.x;
    int idx = blockIdx.x * SCAN_TILE + t * 4;
    int s = 0;
    if (idx + 3 < n) {
        int4 c = *reinterpret_cast<const int4*>(counts + idx);
        s = c.x + c.y + c.z + c.w;
    } else if (idx < n) {
        s = counts[idx];
        if (idx + 1 < n) s += counts[idx + 1];
        if (idx + 2 < n) s += counts[idx + 2];
    }
    sdata[t] = s;
    __syncthreads();
    for (int off = SCAN_BLOCK / 2; off > 0; off >>= 1) {
        if (t < off) sdata[t] += sdata[t + off];
        __syncthreads();
    }
    if (t == 0) block_sums[blockIdx.x] = sdata[0];
}

__global__ void scan_block_offsets(int* __restrict__ block_sums,
                                   int* __restrict__ row_ptr,
                                   int nb, int n) {
    __shared__ int sdata[SCAN_BLOCK];
    int t = threadIdx.x;
    int chunk = (nb + SCAN_BLOCK - 1) / SCAN_BLOCK;
    int lo = t * chunk;
    int hi = min(lo + chunk, nb);
    int s = 0;
    for (int i = lo; i < hi; ++i) s += block_sums[i];
    sdata[t] = s;
    __syncthreads();
    for (int off = 1; off < SCAN_BLOCK; off <<= 1) {
        int u = (t >= off) ? sdata[t - off] : 0;
        __syncthreads();
        sdata[t] += u;
        __syncthreads();
    }
    int run = sdata[t] - s;
    for (int i = lo; i < hi; ++i) {
        int v = block_sums[i];
        block_sums[i] = run;
        run += v;
    }
    if (t == SCAN_BLOCK - 1) row_ptr[n] = sdata[SCAN_BLOCK - 1];
}

// Stage C: exclusive scan of counts -> row_ptr only.
__global__ void scan_apply(const int* __restrict__ counts,
                           const int* __restrict__ block_offsets,
                           int* __restrict__ row_ptr,
                           int n) {
    __shared__ int sdata[SCAN_BLOCK];
    int t = threadIdx.x;
    int idx = blockIdx.x * SCAN_TILE + t * 4;
    int v0 = 0, v1 = 0, v2 = 0, v3 = 0;
    if (idx + 3 < n) {
        int4 c = *reinterpret_cast<const int4*>(counts + idx);
        v0 = c.x; v1 = c.y; v2 = c.z; v3 = c.w;
    } else if (idx < n) {
        v0 = counts[idx];
        if (idx + 1 < n) v1 = counts[idx + 1];
        if (idx + 2 < n) v2 = counts[idx + 2];
    }
    int s = v0 + v1 + v2 + v3;
    sdata[t] = s;
    __syncthreads();
    for (int off = 1; off < SCAN_BLOCK; off <<= 1) {
        int u = (t >= off) ? sdata[t - off] : 0;
        __syncthreads();
        sdata[t] += u;
        __syncthreads();
    }
    int run = sdata[t] - s + block_offsets[blockIdx.x];
    if (idx < n)     { row_ptr[idx]     = run; run += v0; }
    if (idx + 1 < n) { row_ptr[idx + 1] = run; run += v1; }
    if (idx + 2 < n) { row_ptr[idx + 2] = run; run += v2; }
    if (idx + 3 < n) { row_ptr[idx + 3] = run; run += v3; }
}

// ---------------------------------------------------------------------------
// Degree-sorted row remap (counting sort over 64 degree bins).
// Waves get 4 same-degree rows -> no chunk-count divergence. Bytes unchanged.
// ---------------------------------------------------------------------------
__global__ void deg_zero(int* __restrict__ bins) {
    if (threadIdx.x < 128) bins[threadIdx.x] = 0;   // bins[64] + cursors[64]
}

__global__ void deg_hist(const int* __restrict__ row_ptr,
                         int* __restrict__ bins, int n) {
    int i = blockIdx.x * blockDim.x + threadIdx.x;
    int stride = gridDim.x * blockDim.x;
    for (; i < n; i += stride) {
        int d = min(row_ptr[i + 1] - row_ptr[i], 63);
        atomicAdd(&bins[d], 1);
    }
}

// single wave: exclusive scan of 64 bins -> cursors
__global__ void deg_scan(const int* __restrict__ bins,
                         int* __restrict__ cursors) {
    __shared__ int sdata[64];
    int t = threadIdx.x;
    sdata[t] = bins[t];
    __syncthreads();
    for (int off = 1; off < 64; off <<= 1) {
        int u = (t >= off) ? sdata[t - off] : 0;
        __syncthreads();
        sdata[t] += u;
        __syncthreads();
    }
    cursors[t] = sdata[t] - bins[t];   // exclusive
}

__global__ void deg_scatter(const int* __restrict__ row_ptr,
                            int* __restrict__ cursors,
                            int* __restrict__ row_order, int n) {
    int i = blockIdx.x * blockDim.x + threadIdx.x;
    int stride = gridDim.x * blockDim.x;
    for (; i < n; i += stride) {
        int d = min(row_ptr[i + 1] - row_ptr[i], 63);
        int pos = atomicAdd(&cursors[d], 1);
        row_order[pos] = i;
    }
}

// CSR build step 4: scatter edges using precomputed rank — NO atomics.
__global__ void scatter_kernel(const int* __restrict__ rows,
                               const int* __restrict__ cols,
                               const float* __restrict__ vals,
                               const int* __restrict__ row_ptr,
                               const int* __restrict__ rank,
                               int2* __restrict__ colval,
                               int E) {
    int i = blockIdx.x * blockDim.x + threadIdx.x;
    int stride = gridDim.x * blockDim.x;
    for (; i < E; i += stride) {
        int pos = row_ptr[rows[i]] + rank[i];
        colval[pos] = make_int2(cols[i], __float_as_int(vals[i]));
    }
}

// ---------------------------------------------------------------------------
// conv0: S0 = item_emb (fp32, nontemporal both ways) AND X0h = fp16 shadow
// (normal store -> cached, it is layer 1's gather source).
// ---------------------------------------------------------------------------
__global__ void convert_copy(const float4* __restrict__ src,
                             float4* __restrict__ s0,
                             float4* __restrict__ xh,
                             size_t n8) {
    size_t stride = (size_t)gridDim.x * blockDim.x;
    for (size_t i = (size_t)blockIdx.x * blockDim.x + threadIdx.x; i < n8; i += stride) {
        float4 a = nt_load4(src + i * 2);
        float4 b = nt_load4(src + i * 2 + 1);
        nt_store4(s0 + i * 2, a);
        nt_store4(s0 + i * 2 + 1, b);
        __half2 h[4];
        h[0] = __floats2half2_rn(a.x, a.y);
        h[1] = __floats2half2_rn(a.z, a.w);
        h[2] = __floats2half2_rn(b.x, b.y);
        h[3] = __floats2half2_rn(b.z, b.w);
        xh[i] = *reinterpret_cast<float4*>(h);
    }
}

// ---------------------------------------------------------------------------
// CSR SpMM with fp16 gather: 16 lanes per row, 4 rows per wave.
// Rows assigned via degree-sorted row_order -> the 4 rows of a wave have
// (near-)equal chunk counts -> no divergent tail.
// ---------------------------------------------------------------------------
template <bool WRITE_SHADOW>
__global__ void spmm_h16(const int* __restrict__ row_ptr,
                         const int* __restrict__ row_order,
                         const int2* __restrict__ colval,
                         const float4* __restrict__ xh,
                         float* __restrict__ y,
                         float4* __restrict__ yh,
                         int n_rows) {
    int tid = (int)((size_t)blockIdx.x * blockDim.x + threadIdx.x);
    int slot = tid >> 4;           // 16 lanes per row
    int li  = threadIdx.x & 15;
    if (slot >= n_rows) return;
    int row = row_order[slot];

    int start = row_ptr[row];
    int end   = row_ptr[row + 1];

    float acc[8] = {0.f, 0.f, 0.f, 0.f, 0.f, 0.f, 0.f, 0.f};

    for (int base = start; base < end; base += 16) {
        int idx = base + li;
        int c = 0; float v = 0.f;
        if (idx < end) {
            int2 cv = colval[idx];
            c = cv.x;
            v = __int_as_float(cv.y);
        }
        int n = min(16, end - base);   // uniform within the 16-lane group

        // Phase 1: issue all gathers (predicated); h[] in registers.
        float4 h[16];
        #pragma unroll
        for (int j = 0; j < 16; ++j) {
            int cj = __shfl(c, j, 16);
            if (j < n) h[j] = xh[(size_t)cj * 16 + li];
        }

        // Phase 2: consume.
        #pragma unroll
        for (int j = 0; j < 16; ++j) {
            if (j < n) {
                float vj = __shfl(v, j, 16);
                const __half2* hp = reinterpret_cast<const __half2*>(&h[j]);
                float2 f0 = __half22float2(hp[0]);
                float2 f1 = __half22float2(hp[1]);
                float2 f2 = __half22float2(hp[2]);
                float2 f3 = __half22float2(hp[3]);
                acc[0] += vj * f0.x; acc[1] += vj * f0.y;
                acc[2] += vj * f1.x; acc[3] += vj * f1.y;
                acc[4] += vj * f2.x; acc[5] += vj * f2.y;
                acc[6] += vj * f3.x; acc[7] += vj * f3.y;
            }
        }
    }

    size_t ob = (size_t)row * 32 + (size_t)(li * 2);   // float4 index
    nt_store4((float4*)y + ob,     make_float4(acc[0], acc[1], acc[2], acc[3]));
    nt_store4((float4*)y + ob + 1, make_float4(acc[4], acc[5], acc[6], acc[7]));

    if (WRITE_SHADOW) {
        __half2 h2[4];
        h2[0] = __floats2half2_rn(acc[0], acc[1]);
        h2[1] = __floats2half2_rn(acc[2], acc[3]);
        h2[2] = __floats2half2_rn(acc[4], acc[5]);
        h2[3] = __floats2half2_rn(acc[6], acc[7]);
        yh[(size_t)row * 16 + li] = *reinterpret_cast<float4*>(h2);
    }
}

// ---------------------------------------------------------------------------
// Final total: T = S0 + S1 + S2 + S3 (pure streaming -> fully nontemporal)
// ---------------------------------------------------------------------------
__global__ void total_kernel(const float4* __restrict__ s0,
                             const float4* __restrict__ s1,
                             const float4* __restrict__ s2,
                             const float4* __restrict__ s3,
                             float4* __restrict__ t,
                             size_t n4) {
    size_t stride = (size_t)gridDim.x * blockDim.x;
    for (size_t i = (size_t)blockIdx.x * blockDim.x + threadIdx.x; i < n4; i += stride) {
        float4 a = nt_load4(s0 + i), b = nt_load4(s1 + i);
        float4 c = nt_load4(s2 + i), d = nt_load4(s3 + i);
        float4 o;
        o.x = a.x + b.x + c.x + d.x;
        o.y = a.y + b.y + c.y + d.y;
        o.z = a.z + b.z + c.z + d.z;
        o.w = a.w + b.w + c.w + d.w;
        nt_store4(t + i, o);
    }
}

extern "C" void kernel_launch(void* const* d_in, const int* in_sizes, int n_in,
                              void* d_out, int out_size, void* d_ws, size_t ws_size,
                              hipStream_t stream) {
    const float* item_emb = (const float*)d_in[0];
    const int*   adj_rows = (const int*)d_in[1];
    const int*   adj_cols = (const int*)d_in[2];
    const float* adj_vals = (const float*)d_in[3];

    const size_t NH = (size_t)in_sizes[0];      // N * 128
    const int    E  = in_sizes[1];              // 1,600,000
    const int    N  = (int)(NH / HIDDEN);       // 100,000

    // d_out layout: [ total | S0 | S1 | S2 | S3 ], each NH floats
    float* T  = (float*)d_out;
    float* S0 = T + NH;
    float* S1 = S0 + NH;
    float* S2 = S1 + NH;
    float* S3 = S2 + NH;

    // Scratch placement inside d_out (stream-order-disjoint lifetimes):
    //   shA (T region):  X0h during L1, then S2h during L3; T written last.
    //   shB (S3 region): S1h during L2; dead before L3 writes fp32 S3.
    //   rank (S1 region, first E ints): build only; dead before L1 writes S1.
    //   bins/cursors (S1 region, after rank): deg-sort scratch, build only.
    float4* shA  = (float4*)T;
    float4* shB  = (float4*)S3;
    int*    rank = (int*)S1;                    // E ints = 6.4 MB << 51 MB
    int*    bins    = (int*)S1 + E;             // 64 ints
    int*    cursors = (int*)S1 + E + 64;        // 64 ints (still << NH ints)

    // Workspace layout — byte-identical footprint to the baseline kernel.
    char* ws = (char*)d_ws;
    int*   row_ptr = (int*)ws;                       ws += ((size_t)(N + 1) * 4 + 15) & ~15ull;
    int*   counts  = (int*)ws;                       ws += ((size_t)N * 4 + 15) & ~15ull;
    int2*  colval  = (int2*)ws;                      // E*8 bytes (old csr_col+csr_val)

    // counts is dead after scan_apply -> reuse as row_order (lives through L3).
    int* row_order = counts;

    const int nb = (N + SCAN_TILE - 1) / SCAN_TILE;  // 98 scan blocks
    // block_sums: tail of colval (same placement as passing rounds 3-8);
    // dead before scatter_kernel overwrites colval.
    int* block_sums = (int*)(colval + E) - nb;

    // ---- CSR build (no atomics in scatter: rank captured during hist) ----
    {
        int block = 256;
        int gridN = min((N + block - 1) / block, 4096);
        int gridE = min((E + block - 1) / block, 8192);
        zero_counts<<<gridN, block, 0, stream>>>(counts, N);
        hist_kernel<<<gridE, block, 0, stream>>>(adj_rows, counts, rank, E);
        scan_partial_sums<<<nb, SCAN_BLOCK, 0, stream>>>(counts, block_sums, N);
        scan_block_offsets<<<1, SCAN_BLOCK, 0, stream>>>(block_sums, row_ptr, nb, N);
        scan_apply<<<nb, SCAN_BLOCK, 0, stream>>>(counts, block_sums, row_ptr, N);
        // degree-sorted row remap (counts now dead -> row_order storage)
        deg_zero<<<1, 128, 0, stream>>>(bins);
        deg_hist<<<gridN, block, 0, stream>>>(row_ptr, bins, N);
        deg_scan<<<1, 64, 0, stream>>>(bins, cursors);
        deg_scatter<<<gridN, block, 0, stream>>>(row_ptr, cursors, row_order, N);
        // edge scatter last (overwrites colval incl. block_sums tail)
        scatter_kernel<<<gridE, block, 0, stream>>>(adj_rows, adj_cols, adj_vals,
                                                    row_ptr, rank, colval, E);
    }

    // ---- S0 copy + fp16(item_emb) shadow ----
    {
        size_t n8 = NH / 8;
        int block = 256;
        int grid = (int)min((n8 + block - 1) / block, (size_t)8192);
        convert_copy<<<grid, block, 0, stream>>>((const float4*)item_emb,
                                                 (float4*)S0, shA, n8);
    }

    // ---- SpMM layers (fp16 gather, fp32 accumulate/output) ----
    {
        int block = 256;                       // 16 rows per block (16 lanes each)
        int grid = (N * 16 + block - 1) / block;
        // L1: gather X0h (shA) -> S1 fp32 (overwrites dead rank/bins) + S1h (shB)
        spmm_h16<true><<<grid, block, 0, stream>>>(row_ptr, row_order, colval, shA, S1, shB, N);
        // L2: gather S1h (shB) -> S2 fp32 + S2h (shA, over dead X0h)
        spmm_h16<true><<<grid, block, 0, stream>>>(row_ptr, row_order, colval, shB, S2, shA, N);
        // L3: gather S2h (shA) -> S3 fp32 (overwrites dead S1h region)
        spmm_h16<false><<<grid, block, 0, stream>>>(row_ptr, row_order, colval, shA, S3, nullptr, N);
    }

    // ---- T = S0 + S1 + S2 + S3 (overwrites dead S2h region) ----
    {
        size_t n4 = NH / 4;
        int block = 256;
        int grid = (int)min((n4 + block - 1) / block, (size_t)8192);
        total_kernel<<<grid, block, 0, stream>>>((const float4*)S0, (const float4*)S1,
                                                 (const float4*)S2, (const float4*)S3,
                                                 (float4*)T, n4);
    }
}